// Round 5
// baseline (99.033 us; speedup 1.0000x reference)
//
#include <hip/hip_runtime.h>

typedef __attribute__((ext_vector_type(8))) short bf16x8;
typedef __attribute__((ext_vector_type(4))) float f32x4;
typedef unsigned short u16;
typedef unsigned int u32;

constexpr int N = 8192;
constexpr int D = 128;
constexpr float CEXP   = 2.8853900817779268f;  // log2(e)/tau, tau = 0.5
constexpr float BSCALE = 1.6986435688113073f;  // sqrt(CEXP) folded into bf16 inputs

#if __has_builtin(__builtin_amdgcn_exp2f)
__device__ __forceinline__ float fexp2(float x) { return __builtin_amdgcn_exp2f(x); }
#else
__device__ __forceinline__ float fexp2(float x) { return exp2f(x); }
#endif

__device__ __forceinline__ u32 f2bf(float x) {
  union { float f; unsigned u; } v;
  v.f = x;
  unsigned r = v.u + 0x7fffu + ((v.u >> 16) & 1u);  // RNE
  return r >> 16;
}

// ---------- fused: fp32->bf16 convert (pre-scaled) + per-row exact dots + zero accums ----------
// one wave per row; lane l handles elements 2l, 2l+1
__global__ void convert_dots_kernel(const float2* __restrict__ z1, const float2* __restrict__ z2,
                                    u32* __restrict__ o1, u32* __restrict__ o2,
                                    float* __restrict__ dotSelf, float* __restrict__ dotCross,
                                    float* __restrict__ zeroBase, float* __restrict__ out) {
  const int tid = threadIdx.x;
  const int row = blockIdx.x * 4 + (tid >> 6);
  const int l = tid & 63;
  const int zidx = blockIdx.x * 256 + tid;
  if (zidx < 3 * N) zeroBase[zidx] = 0.0f;  // rowRefl | rowBet | colBet
  if (zidx == 0) out[0] = 0.0f;

  float2 a = z1[row * 64 + l];
  float2 b = z2[row * 64 + l];
  o1[row * 64 + l] = f2bf(a.x * BSCALE) | (f2bf(a.y * BSCALE) << 16);
  o2[row * 64 + l] = f2bf(b.x * BSCALE) | (f2bf(b.y * BSCALE) << 16);

  float d11 = a.x * a.x + a.y * a.y;  // |z1_i|^2 partial
  float d12 = a.x * b.x + a.y * b.y;  // z1_i . z2_i partial
#pragma unroll
  for (int mask = 1; mask < 64; mask <<= 1) {
    d11 += __shfl_xor(d11, mask);
    d12 += __shfl_xor(d12, mask);
  }
  if (l == 0) {
    dotSelf[row] = d11;
    dotCross[row] = d12;
  }
}

// ---------- fused GEMM + exp + row/col sums, NO LDS: B fragments straight from L2 ----------
// grid: 2048 = bi(128: 64 A-rows) x jg(16). jg<8: refl (B=z1 -> rowRefl);
// jg>=8: between (B=z2 -> rowBet+colBet). Col range (jg&7)*1024.
// Wave w handles cols (jg&7)*1024 + g*64 + w*16 for g=0..15; all 4 waves share the A rows.
// Both A and B fragments use the identical contiguous-8 (row, kk*32+lg*8) addressing ->
// any internal MFMA k-permutation cancels between operands.
__global__ __launch_bounds__(256, 4) void gemm_kernel(const u16* __restrict__ z1b,
                                                      const u16* __restrict__ z2b,
                                                      float* __restrict__ rowRefl,
                                                      float* __restrict__ rowBet,
                                                      float* __restrict__ colBet) {
  const int tid = threadIdx.x;
  const int l = tid & 63, w = tid >> 6;
  const int lr = l & 15, lg = l >> 4;
  const int bi = blockIdx.x >> 4;
  const int jg = blockIdx.x & 15;
  const bool between = jg >= 8;
  const u16* bsrc = between ? z2b : z1b;
  const int col0 = (jg & 7) * 1024 + w * 16;  // this wave's first col for g=0 (step 64 per g)

  // ---- A fragments: rows bi*64 + m*16 + lr, k = kk*32 + lg*8 (registers, reused 16x) ----
  bf16x8 af[4][4];
  {
    const char* abase = (const char*)(z1b + (size_t)(bi * 64 + lr) * D + lg * 8);
#pragma unroll
    for (int m = 0; m < 4; ++m)
#pragma unroll
      for (int kk = 0; kk < 4; ++kk)
        af[m][kk] = *(const bf16x8*)(abase + m * 16 * 256 + kk * 64);
  }

  float rowp[4][4];
#pragma unroll
  for (int m = 0; m < 4; ++m)
#pragma unroll
    for (int r = 0; r < 4; ++r) rowp[m][r] = 0.f;

  // per-lane B offset within a 16-row col-group: row lr, k-chunk lg
  const char* bbase = (const char*)bsrc + (size_t)(col0 + lr) * 256 + lg * 16;

  for (int g = 0; g < 16; ++g) {
    const char* bp = bbase + (size_t)g * 64 * 256;  // 64 cols per g step
    bf16x8 bfr[4];
#pragma unroll
    for (int kk = 0; kk < 4; ++kk) bfr[kk] = *(const bf16x8*)(bp + kk * 64);

    f32x4 acc[4];
    const f32x4 z4 = {0.f, 0.f, 0.f, 0.f};
#pragma unroll
    for (int m = 0; m < 4; ++m)
      acc[m] = __builtin_amdgcn_mfma_f32_16x16x32_bf16(af[m][0], bfr[0], z4, 0, 0, 0);
#pragma unroll
    for (int kk = 1; kk < 4; ++kk)
#pragma unroll
      for (int m = 0; m < 4; ++m)
        acc[m] = __builtin_amdgcn_mfma_f32_16x16x32_bf16(af[m][kk], bfr[kk], acc[m], 0, 0, 0);

    // exp + accumulate. C/D layout: col = lane&15, row (within m-frag) = lg*4 + r.
    if (!between) {
#pragma unroll
      for (int m = 0; m < 4; ++m)
#pragma unroll
        for (int r = 0; r < 4; ++r) rowp[m][r] += fexp2(acc[m][r]);
    } else {
      float colp = 0.f;
#pragma unroll
      for (int m = 0; m < 4; ++m) {
        float v0 = fexp2(acc[m][0]), v1 = fexp2(acc[m][1]);
        float v2 = fexp2(acc[m][2]), v3 = fexp2(acc[m][3]);
        rowp[m][0] += v0;
        rowp[m][1] += v1;
        rowp[m][2] += v2;
        rowp[m][3] += v3;
        colp += (v0 + v1) + (v2 + v3);
      }
      // col sums: reduce over lane-groups (rows); lanes l<16 hold 16 distinct cols
      colp += __shfl_xor(colp, 16);
      colp += __shfl_xor(colp, 32);
      if (l < 16) atomicAdd(&colBet[col0 + g * 64 + l], colp);
    }
  }

  // ---- deferred row reduction: shuffle over the 16 col-lanes, one atomic per row ----
  float* rowdst = between ? rowBet : rowRefl;
#pragma unroll
  for (int m = 0; m < 4; ++m)
#pragma unroll
    for (int r = 0; r < 4; ++r) {
      float s = rowp[m][r];
      s += __shfl_xor(s, 1);
      s += __shfl_xor(s, 2);
      s += __shfl_xor(s, 4);
      s += __shfl_xor(s, 8);
      if (lr == 0) atomicAdd(&rowdst[bi * 64 + m * 16 + lg * 4 + r], s);
    }
}

// ---------- per-row loss (exact fp32 diagonals) + mean ----------
__global__ void final_kernel(const float* __restrict__ rowRefl, const float* __restrict__ rowBet,
                             const float* __restrict__ colBet, const float* __restrict__ dotSelf,
                             const float* __restrict__ dotCross, float* __restrict__ out) {
  const int r = blockIdx.x * 256 + threadIdx.x;  // 32 blocks x 256 = 8192
  float rdiag = fexp2(dotSelf[r] * CEXP);        // exp(|z1_i|^2/tau), exact fp32
  float base = rowRefl[r] - rdiag;
  // -log(pos) = -d12/tau = -2*d12 exactly (no exp/log roundtrip)
  float loss = 0.5f * (logf(base + rowBet[r]) + logf(base + colBet[r])) - 2.0f * dotCross[r];
  loss *= (1.0f / (float)N);
#pragma unroll
  for (int mask = 1; mask < 64; mask <<= 1) loss += __shfl_xor(loss, mask);
  if ((threadIdx.x & 63) == 0) atomicAdd(out, loss);
}

extern "C" void kernel_launch(void* const* d_in, const int* in_sizes, int n_in,
                              void* d_out, int out_size, void* d_ws, size_t ws_size,
                              hipStream_t stream) {
  const float* z1 = (const float*)d_in[0];
  const float* z2 = (const float*)d_in[1];
  float* out = (float*)d_out;
  char* ws = (char*)d_ws;

  // ws: z1b(2MB) | z2b(2MB) | rowRefl(N) | rowBet(N) | colBet(N) | dotSelf(N) | dotCross(N)
  u16* z1b = (u16*)ws;
  u16* z2b = (u16*)(ws + (size_t)N * D * 2);
  float* rowRefl = (float*)(ws + (size_t)2 * N * D * 2);
  float* rowBet = rowRefl + N;
  float* colBet = rowBet + N;
  float* dotSelf = colBet + N;
  float* dotCross = dotSelf + N;

  convert_dots_kernel<<<N / 4, 256, 0, stream>>>((const float2*)z1, (const float2*)z2,
                                                 (u32*)z1b, (u32*)z2b, dotSelf, dotCross,
                                                 rowRefl, out);
  gemm_kernel<<<2048, 256, 0, stream>>>(z1b, z2b, rowRefl, rowBet, colBet);
  final_kernel<<<N / 256, 256, 0, stream>>>(rowRefl, rowBet, colBet, dotSelf, dotCross, out);
}

// Round 6
// 65.243 us; speedup vs baseline: 1.5179x; 1.5179x over previous
//
#include <hip/hip_runtime.h>

typedef __attribute__((ext_vector_type(8))) short bf16x8;
typedef __attribute__((ext_vector_type(4))) float f32x4;
typedef unsigned short u16;
typedef unsigned int u32;

constexpr int N = 8192;
constexpr int D = 128;
constexpr float CEXP   = 2.8853900817779268f;  // log2(e)/tau, tau = 0.5
constexpr float BSCALE = 1.6986435688113073f;  // sqrt(CEXP) folded into bf16 inputs

#if __has_builtin(__builtin_amdgcn_exp2f)
__device__ __forceinline__ float fexp2(float x) { return __builtin_amdgcn_exp2f(x); }
#else
__device__ __forceinline__ float fexp2(float x) { return exp2f(x); }
#endif

__device__ __forceinline__ u32 f2bf(float x) {
  union { float f; unsigned u; } v;
  v.f = x;
  unsigned r = v.u + 0x7fffu + ((v.u >> 16) & 1u);  // RNE
  return r >> 16;
}

// ---------- fused: fp32->bf16 convert (pre-scaled) + per-row exact dots + zero accums ----------
// one wave per row; lane l handles elements 2l, 2l+1  (verified R5)
__global__ void convert_dots_kernel(const float2* __restrict__ z1, const float2* __restrict__ z2,
                                    u32* __restrict__ o1, u32* __restrict__ o2,
                                    float* __restrict__ dotSelf, float* __restrict__ dotCross,
                                    float* __restrict__ zeroBase, float* __restrict__ out) {
  const int tid = threadIdx.x;
  const int row = blockIdx.x * 4 + (tid >> 6);
  const int l = tid & 63;
  const int zidx = blockIdx.x * 256 + tid;
  if (zidx < 3 * N) zeroBase[zidx] = 0.0f;  // rowRefl | rowBet | colBet
  if (zidx == 0) out[0] = 0.0f;

  float2 a = z1[row * 64 + l];
  float2 b = z2[row * 64 + l];
  o1[row * 64 + l] = f2bf(a.x * BSCALE) | (f2bf(a.y * BSCALE) << 16);
  o2[row * 64 + l] = f2bf(b.x * BSCALE) | (f2bf(b.y * BSCALE) << 16);

  float d11 = a.x * a.x + a.y * a.y;  // |z1_i|^2 partial
  float d12 = a.x * b.x + a.y * b.y;  // z1_i . z2_i partial
#pragma unroll
  for (int mask = 1; mask < 64; mask <<= 1) {
    d11 += __shfl_xor(d11, mask);
    d12 += __shfl_xor(d12, mask);
  }
  if (l == 0) {
    dotSelf[row] = d11;
    dotCross[row] = d12;
  }
}

// ---------- async stage 16KB strip (64 rows x 256B): linear LDS dest, pre-swizzled src ----------
// swizzled layout: logical (row, chunk c) lives at byte row*256 + ((c ^ (row&15))<<4)  (verified R2/R4)
__device__ __forceinline__ void stage16k(char* lds, const char* gsrc, int soff, int doff) {
#pragma unroll
  for (int s = 0; s < 4; ++s) {
    __builtin_amdgcn_global_load_lds(
        (const __attribute__((address_space(1))) u32*)(gsrc + soff + s * 4096),
        (__attribute__((address_space(3))) u32*)(lds + doff + s * 4096), 16, 0, 0);
  }
}

// ---------- fused GEMM(z1_I x {z1,z2}_J^T) + exp + row/col sums ----------
// grid: 2048 = bi(128: 64 A-rows) x jg(16). jg<8: refl (B=z1 -> rowRefl);
// jg>=8: between (B=z2 -> rowBet+colBet). Col range (jg&7)*1024, 16 strips of 64 cols.
// A staged to LDS once, read into af[4][4] registers (LDS-fed => compiler cannot sink the
// loads into the loop: the buffer is clobbered by B strips). Each wave owns 16 cols/strip:
// 4 ds_read_b128 -> 16 MFMA (m_rep=4). 32KB LDS double-buffer => 4 blocks/CU.
__global__ __launch_bounds__(256, 4) void gemm_kernel(const u16* __restrict__ z1b,
                                                      const u16* __restrict__ z2b,
                                                      float* __restrict__ rowRefl,
                                                      float* __restrict__ rowBet,
                                                      float* __restrict__ colBet) {
  __shared__ __align__(16) char B0[16384];
  __shared__ __align__(16) char B1[16384];
  const int tid = threadIdx.x;
  const int l = tid & 63, w = tid >> 6;
  const int lr = l & 15, lg = l >> 4;
  const int bi = blockIdx.x >> 4;
  const int jg = blockIdx.x & 15;
  const bool between = jg >= 8;
  const u16* bsrc = between ? z2b : z1b;
  const int colbase = (jg & 7) * 1024;

  // staging offsets: linear LDS dest, inverse-swizzled global src
  const int soff = (tid >> 4) * 256 + (((tid & 15) ^ (tid >> 4)) << 4);
  const int doff = tid * 16;

  // ---- stage A (rows bi*64..+63, 16KB) into B0, read to registers through swizzle ----
  stage16k(B0, (const char*)(z1b + (size_t)bi * 64 * D), soff, doff);
  __syncthreads();
  bf16x8 af[4][4];  // [m][kk]: row = bi*64 + m*16 + lr, k-chunk kk*4+lg
#pragma unroll
  for (int m = 0; m < 4; ++m)
#pragma unroll
    for (int kk = 0; kk < 4; ++kk)
      af[m][kk] = *(const bf16x8*)(B0 + (m * 16 + lr) * 256 + (((kk * 4 + lg) ^ lr) << 4));
  __syncthreads();  // all waves done reading A

  stage16k(B0, (const char*)(bsrc + (size_t)colbase * D), soff, doff);  // prologue strip 0

  float rowp[4][4];
#pragma unroll
  for (int m = 0; m < 4; ++m)
#pragma unroll
    for (int r = 0; r < 4; ++r) rowp[m][r] = 0.f;

  for (int t = 0; t < 16; ++t) {
    __syncthreads();  // strip t staged (barrier drains vmcnt); prev-strip readers done
    const char* cur = (t & 1) ? B1 : B0;
    char* nxt = (t & 1) ? B0 : B1;
    if (t + 1 < 16)
      stage16k(nxt, (const char*)(bsrc + (size_t)(colbase + (t + 1) * 64) * D), soff, doff);

    // this wave's 16 cols within the strip: local rows w*16 + lr (row&15 == lr)
    bf16x8 bfr[4];
#pragma unroll
    for (int kk = 0; kk < 4; ++kk)
      bfr[kk] = *(const bf16x8*)(cur + (w * 16 + lr) * 256 + (((kk * 4 + lg) ^ lr) << 4));

    f32x4 acc[4];
    const f32x4 z4 = {0.f, 0.f, 0.f, 0.f};
#pragma unroll
    for (int m = 0; m < 4; ++m)
      acc[m] = __builtin_amdgcn_mfma_f32_16x16x32_bf16(af[m][0], bfr[0], z4, 0, 0, 0);
#pragma unroll
    for (int kk = 1; kk < 4; ++kk)
#pragma unroll
      for (int m = 0; m < 4; ++m)
        acc[m] = __builtin_amdgcn_mfma_f32_16x16x32_bf16(af[m][kk], bfr[kk], acc[m], 0, 0, 0);

    // exp + accumulate. C/D layout: col = lane&15, row (within m-frag) = lg*4 + r.
    if (!between) {
#pragma unroll
      for (int m = 0; m < 4; ++m)
#pragma unroll
        for (int r = 0; r < 4; ++r) rowp[m][r] += fexp2(acc[m][r]);
    } else {
      float colp = 0.f;
#pragma unroll
      for (int m = 0; m < 4; ++m) {
        float v0 = fexp2(acc[m][0]), v1 = fexp2(acc[m][1]);
        float v2 = fexp2(acc[m][2]), v3 = fexp2(acc[m][3]);
        rowp[m][0] += v0;
        rowp[m][1] += v1;
        rowp[m][2] += v2;
        rowp[m][3] += v3;
        colp += (v0 + v1) + (v2 + v3);
      }
      // col sums: reduce over lane-groups (rows); lanes l<16 hold the 16 cols
      colp += __shfl_xor(colp, 16);
      colp += __shfl_xor(colp, 32);
      if (l < 16) atomicAdd(&colBet[colbase + t * 64 + w * 16 + l], colp);
    }
  }

  // ---- deferred row reduction: shuffle over the 16 col-lanes, one atomic per row ----
  float* rowdst = between ? rowBet : rowRefl;
#pragma unroll
  for (int m = 0; m < 4; ++m)
#pragma unroll
    for (int r = 0; r < 4; ++r) {
      float s = rowp[m][r];
      s += __shfl_xor(s, 1);
      s += __shfl_xor(s, 2);
      s += __shfl_xor(s, 4);
      s += __shfl_xor(s, 8);
      if (lr == 0) atomicAdd(&rowdst[bi * 64 + m * 16 + lg * 4 + r], s);
    }
}

// ---------- per-row loss (exact fp32 diagonals) + mean  (verified R5) ----------
__global__ void final_kernel(const float* __restrict__ rowRefl, const float* __restrict__ rowBet,
                             const float* __restrict__ colBet, const float* __restrict__ dotSelf,
                             const float* __restrict__ dotCross, float* __restrict__ out) {
  const int r = blockIdx.x * 256 + threadIdx.x;  // 32 blocks x 256 = 8192
  float rdiag = fexp2(dotSelf[r] * CEXP);        // exp(|z1_i|^2/tau), exact fp32
  float base = rowRefl[r] - rdiag;
  // -log(pos) = -d12/tau = -2*d12 exactly (no exp/log roundtrip)
  float loss = 0.5f * (logf(base + rowBet[r]) + logf(base + colBet[r])) - 2.0f * dotCross[r];
  loss *= (1.0f / (float)N);
#pragma unroll
  for (int mask = 1; mask < 64; mask <<= 1) loss += __shfl_xor(loss, mask);
  if ((threadIdx.x & 63) == 0) atomicAdd(out, loss);
}

extern "C" void kernel_launch(void* const* d_in, const int* in_sizes, int n_in,
                              void* d_out, int out_size, void* d_ws, size_t ws_size,
                              hipStream_t stream) {
  const float* z1 = (const float*)d_in[0];
  const float* z2 = (const float*)d_in[1];
  float* out = (float*)d_out;
  char* ws = (char*)d_ws;

  // ws: z1b(2MB) | z2b(2MB) | rowRefl(N) | rowBet(N) | colBet(N) | dotSelf(N) | dotCross(N)
  u16* z1b = (u16*)ws;
  u16* z2b = (u16*)(ws + (size_t)N * D * 2);
  float* rowRefl = (float*)(ws + (size_t)2 * N * D * 2);
  float* rowBet = rowRefl + N;
  float* colBet = rowBet + N;
  float* dotSelf = colBet + N;
  float* dotCross = dotSelf + N;

  convert_dots_kernel<<<N / 4, 256, 0, stream>>>((const float2*)z1, (const float2*)z2,
                                                 (u32*)z1b, (u32*)z2b, dotSelf, dotCross,
                                                 rowRefl, out);
  gemm_kernel<<<2048, 256, 0, stream>>>(z1b, z2b, rowRefl, rowBet, colBet);
  final_kernel<<<N / 256, 256, 0, stream>>>(rowRefl, rowBet, colBet, dotSelf, dotCross, out);
}